// Round 2
// baseline (7021.638 us; speedup 1.0000x reference)
//
#include <hip/hip_runtime.h>
#include <hip/hip_bf16.h>
#include <math.h>

#define BATCH 256
#define DIM 1024
#define KG 7
#define VOCAB 32000
#define NBLK_DEQ 112

typedef unsigned short u16;
typedef unsigned int u32;
typedef __attribute__((ext_vector_type(8))) short short8v;
typedef __attribute__((ext_vector_type(4))) float f32x4;

__device__ __forceinline__ int iclamp(int v, int lo, int hi) { return v < lo ? lo : (v > hi ? hi : v); }

__device__ __forceinline__ u16 f2bf(float f) {
    union { float f; u32 u; } x; x.f = f;
    u32 r = x.u + 0x7FFFu + ((x.u >> 16) & 1u);   // round-to-nearest-even
    return (u16)(r >> 16);
}
__device__ __forceinline__ float bf2f(u16 b) {
    union { u32 u; float f; } x; x.u = ((u32)b) << 16;
    return x.f;
}

// ---------------- block reduce (256 threads, 4 waves) ----------------
__device__ __forceinline__ float block_reduce(float v, float* sm) {
    #pragma unroll
    for (int o = 32; o > 0; o >>= 1) v += __shfl_down(v, o, 64);
    int wid = threadIdx.x >> 6, lane = threadIdx.x & 63;
    if (lane == 0) sm[wid] = v;
    __syncthreads();
    if (threadIdx.x == 0) sm[0] = sm[0] + sm[1] + sm[2] + sm[3];
    __syncthreads();
    float r = sm[0];
    __syncthreads();
    return r;
}

// ---------------- addr row inverse norms ----------------
__global__ void addr_norm_k(const float* __restrict__ addr, float* __restrict__ addr_inv) {
    __shared__ float sm[4];
    for (int k = 0; k < KG; k++) {
        float s = 0.f;
        for (int d = threadIdx.x; d < DIM; d += 256) { float a = addr[k * DIM + d]; s += a * a; }
        float tot = block_reduce(s, sm);
        if (threadIdx.x == 0) addr_inv[k] = 1.0f / fmaxf(sqrtf(tot), 1e-12f);
        __syncthreads();
    }
}

// ---------------- per-sample: f_emb, xcat(h,f), scores->pi, idx, gamma ----------------
__global__ void sample_k(const float* __restrict__ h, const float* __restrict__ fib_s,
                         const float* __restrict__ fib_e, const int* __restrict__ tok,
                         const float* __restrict__ opemb, const float* __restrict__ num_w,
                         const float* __restrict__ num_b, const float* __restrict__ addr,
                         const float* __restrict__ fs_w, const float* __restrict__ fs_b,
                         const float* __restrict__ fe_w, const float* __restrict__ fe_b,
                         const float* __restrict__ c1w, const float* __restrict__ c1b,
                         const float* __restrict__ c2w, const float* __restrict__ c2b,
                         const float* __restrict__ addr_inv, float* __restrict__ xcat,
                         float* __restrict__ gamma_ws, int* __restrict__ kidx,
                         float* __restrict__ pi_out) {
    int b = blockIdx.x;
    int t = tok[b];
    bool ctrl = (t < 7);
    int tcl = iclamp(t, 0, 6);
    float numv = (float)t - 7.0f;
    float fsv = fib_s[b], fev = fib_e[b];
    float vv = 0.f, dot[KG];
    #pragma unroll
    for (int k = 0; k < KG; k++) dot[k] = 0.f;
    for (int d = threadIdx.x; d < DIM; d += 256) {
        float femb = tanhf(fsv * fs_w[d] + fs_b[d] + fev * fe_w[d] + fe_b[d]);
        float hf = h[b * DIM + d];
        xcat[b * 2048 + d] = hf;
        xcat[b * 2048 + DIM + d] = femb;
        float v;
        if (ctrl) v = opemb[tcl * DIM + d];
        else      v = numv * num_w[d] + num_b[d] + femb;
        vv += v * v;
        #pragma unroll
        for (int k = 0; k < KG; k++) dot[k] += v * addr[k * DIM + d];
    }
    __shared__ float sm[4];
    vv = block_reduce(vv, sm);
    float sc[KG];
    for (int k = 0; k < KG; k++) sc[k] = block_reduce(dot[k], sm);
    if (threadIdx.x == 0) {
        float inv_v = 1.0f / fmaxf(sqrtf(vv), 1e-12f);
        float m = -1e30f;
        for (int k = 0; k < KG; k++) { sc[k] = 5.0f * sc[k] * inv_v * addr_inv[k]; m = fmaxf(m, sc[k]); }
        float se = 0.f, p[KG];
        for (int k = 0; k < KG; k++) { p[k] = expf(sc[k] - m); se += p[k]; }
        float ent = 0.f, best = -1.f;
        int idx = 0;
        for (int k = 0; k < KG; k++) {
            p[k] /= se;
            ent -= p[k] * logf(p[k] + 1e-8f);
            if (p[k] > best) { best = p[k]; idx = k; }
        }
        float acc = c2b[0];
        for (int j = 0; j < 16; j++) {
            float x = fmaxf(0.0f, ent * c1w[j * 2 + 0] + c1b[j]);
            acc += x * c2w[j];
        }
        float g = (acc > 20.f) ? acc : log1pf(expf(acc));  // softplus
        gamma_ws[b] = g;
        kidx[b] = idx;
        for (int k = 0; k < KG; k++) pi_out[b * KG + k] = p[k];
    }
}

// ---------------- group samples by expert, build 16-row tiles ----------------
__global__ void group_k(const int* __restrict__ kidx, int* __restrict__ order,
                        int* __restrict__ tile_k, int* __restrict__ tile_r0,
                        int* __restrict__ tile_nr, int* __restrict__ ntiles,
                        int* __restrict__ cnt_g, int* __restrict__ base_g,
                        unsigned* __restrict__ bar) {
    __shared__ int kk[BATCH];
    __shared__ int cnt[KG];
    __shared__ int base_s[KG];
    int tid = threadIdx.x;
    kk[tid] = iclamp(kidx[tid], 0, 6);
    __syncthreads();
    if (tid < KG) { int c = 0; for (int i = 0; i < BATCH; i++) c += (kk[i] == tid); cnt[tid] = c; }
    __syncthreads();
    if (tid == 0) { int s = 0; for (int k = 0; k < KG; k++) { base_s[k] = s; s += cnt[k]; } *bar = 0u; }
    __syncthreads();
    if (tid < KG) { cnt_g[tid] = cnt[tid]; base_g[tid] = base_s[tid]; }
    int mk = kk[tid];
    int rank = 0;
    for (int i = 0; i < tid; i++) rank += (kk[i] == mk);
    order[base_s[mk] + rank] = tid;
    if (tid == 0) {
        int nt = 0;
        for (int k = 0; k < KG; k++)
            for (int off = 0; off < cnt[k]; off += 16) {
                tile_k[nt] = k; tile_r0[nt] = base_s[k] + off; tile_nr[nt] = min(16, cnt[k] - off); nt++;
            }
        *ntiles = nt;
    }
}

// ---------------- one-time: transpose+convert W[k][d][e] -> Wt[k][e][d] bf16 ----------------
__global__ __launch_bounds__(256) void convt_k(const float* __restrict__ W, u16* __restrict__ Wt) {
    int kg = blockIdx.z;
    int d0 = blockIdx.x * 64;
    int e0 = blockIdx.y * 64;
    __shared__ float T[64][68];
    int tid = threadIdx.x;
    {
        int i = tid >> 2;
        int j4 = (tid & 3) * 16;
        const float* src = W + (size_t)kg * 1048576 + (size_t)(d0 + i) * 1024 + e0 + j4;
        #pragma unroll
        for (int j = 0; j < 4; j++) {
            float4 v = *reinterpret_cast<const float4*>(src + j * 4);
            *reinterpret_cast<float4*>(&T[i][j4 + j * 4]) = v;
        }
    }
    __syncthreads();
    {
        int e = tid >> 2;
        int d4 = (tid & 3) * 16;
        u16 tmp[16];
        #pragma unroll
        for (int x = 0; x < 16; x++) tmp[x] = f2bf(T[d4 + x][e]);
        u16* dst = Wt + (size_t)kg * 1048576 + (size_t)(e0 + e) * 1024 + d0 + d4;
        *reinterpret_cast<short8v*>(dst) = *reinterpret_cast<short8v*>(tmp);
        *reinterpret_cast<short8v*>(dst + 8) = *reinterpret_cast<short8v*>(tmp + 8);
    }
}

// ---------------- fp32 grouped GEMM (one-time U/V -> c computation) ----------------
__global__ __launch_bounds__(256) void gg_k(const float* __restrict__ Abuf, int lda,
                                            const float* __restrict__ Bbase,
                                            const float* __restrict__ Cadd,
                                            float* __restrict__ outz, int act,
                                            const int* __restrict__ order,
                                            const int* __restrict__ tile_k,
                                            const int* __restrict__ tile_r0,
                                            const int* __restrict__ tile_nr,
                                            const int* __restrict__ ntiles) {
    int t = blockIdx.y;
    int nt = iclamp(*ntiles, 0, 22);
    if (t >= nt) return;
    int kg = iclamp(tile_k[t], 0, 6);
    int nr = iclamp(tile_nr[t], 1, 16);
    int r0 = iclamp(tile_r0[t], 0, 255);
    int n0 = blockIdx.x * 128;
    __shared__ int rows[16];
    __shared__ float As[16][33];
    __shared__ float Bs[32][128];
    int tid = threadIdx.x;
    if (tid < 16) {
        int ro = iclamp(r0 + min(tid, nr - 1), 0, 255);
        rows[tid] = iclamp(order[ro], 0, 255);
    }
    __syncthreads();
    const float* Bmat = Bbase + (size_t)kg * DIM * DIM;
    float acc[2][4] = {};
    int tr = tid >> 5;
    int tc = tid & 31;
    for (int k0 = 0; k0 < DIM; k0 += 32) {
        {
            int e = tid;
            #pragma unroll
            for (int rep = 0; rep < 2; rep++) {
                int i = e >> 5, kx = e & 31;
                As[i][kx] = Abuf[(size_t)rows[i] * lda + k0 + kx];
                e += 256;
            }
        }
        {
            #pragma unroll
            for (int rep = 0; rep < 16; rep++) {
                int e = tid + rep * 256;
                int dd = e >> 7, cc = e & 127;
                Bs[dd][cc] = Bmat[(size_t)(k0 + dd) * DIM + n0 + cc];
            }
        }
        __syncthreads();
        #pragma unroll
        for (int kx = 0; kx < 32; kx++) {
            float a0 = As[tr][kx], a1 = As[tr + 8][kx];
            float b0 = Bs[kx][tc], b1 = Bs[kx][tc + 32], b2v = Bs[kx][tc + 64], b3 = Bs[kx][tc + 96];
            acc[0][0] += a0 * b0; acc[0][1] += a0 * b1; acc[0][2] += a0 * b2v; acc[0][3] += a0 * b3;
            acc[1][0] += a1 * b0; acc[1][1] += a1 * b1; acc[1][2] += a1 * b2v; acc[1][3] += a1 * b3;
        }
        __syncthreads();
    }
    #pragma unroll
    for (int ii = 0; ii < 2; ii++) {
        int i = tr + ii * 8;
        if (i < nr) {
            int r = rows[i];
            #pragma unroll
            for (int j = 0; j < 4; j++) {
                int c = n0 + tc + j * 32;
                float v = acc[ii][j];
                if (Cadd) v += Cadd[(size_t)r * DIM + c];
                if (act == 1) v = tanhf(v);
                outz[(size_t)r * DIM + c] = v;
            }
        }
    }
}

// ---------------- grid barrier (monotonic counter, device-scope) ----------------
__device__ __forceinline__ void grid_barrier(unsigned* bar, unsigned target) {
    __threadfence();              // drain own stores; wb/inv L2 (cross-XCD visibility)
    __syncthreads();
    if (threadIdx.x == 0) {
        __hip_atomic_fetch_add(bar, 1u, __ATOMIC_ACQ_REL, __HIP_MEMORY_SCOPE_AGENT);
        unsigned v;
        do {
            __builtin_amdgcn_s_sleep(2);
            v = __hip_atomic_load(bar, __ATOMIC_ACQUIRE, __HIP_MEMORY_SCOPE_AGENT);
        } while (v < target);
    }
    __syncthreads();
    __threadfence();              // invalidate stale L1/L2 before next reads
}

// ---------------- persistent DEQ: z = tanh(c + z @ W[k]) x 40, W LDS-resident ----------------
// 112 blocks = 7 experts x 16 col-panels of 64. One block/CU (132KB LDS) -> all co-resident.
// Math is instruction-identical to the previous ggm_k chain (same mfma order, same f2bf).
__global__ __launch_bounds__(256, 1) void deq_k(const float* __restrict__ c_buf,
                                                u16* __restrict__ za, u16* __restrict__ zb,
                                                const u16* __restrict__ Wt,
                                                const int* __restrict__ order,
                                                const int* __restrict__ cnt_g,
                                                const int* __restrict__ base_g,
                                                unsigned* __restrict__ bar) {
    int kg = blockIdx.x >> 4;          // 0..6
    int c0 = (blockIdx.x & 15) << 6;   // 0..960
    int tid = threadIdx.x;
    __shared__ __align__(16) u16 Wl[64 * 1032];   // 64 cols x 1024 K, rows padded to 1032
    __shared__ int rows_l[256];
    __shared__ int meta[2];
    if (tid == 0) meta[0] = iclamp(cnt_g[kg], 0, 256);
    if (tid == 1) meta[1] = iclamp(base_g[kg], 0, 255);
    rows_l[tid] = iclamp(order[tid], 0, 255);
    // stage W panel once (cols c0..c0+63 are rows of Wt[kg])
    {
        const u16* src = Wt + (size_t)kg * 1048576 + (size_t)c0 * 1024;
        #pragma unroll
        for (int i = 0; i < 32; i++) {
            int ch = i * 256 + tid;           // 8192 chunks of 8 u16
            int e = ch >> 7, q = ch & 127;
            *reinterpret_cast<short8v*>(Wl + e * 1032 + q * 8) =
                *reinterpret_cast<const short8v*>(src + (size_t)e * 1024 + q * 8);
        }
    }
    __syncthreads();
    int cnt = meta[0], base = meta[1];
    int nt = (cnt + 15) >> 4;
    // application 1: z1 = tanh(c) on (my rows x my 64 cols)
    for (int i = tid; i < cnt * 64; i += 256) {
        int rl = i >> 6, cc = i & 63;
        int r = rows_l[iclamp(base + rl, 0, 255)];
        za[(size_t)r * 1024 + c0 + cc] = f2bf(tanhf(c_buf[(size_t)r * 1024 + c0 + cc]));
    }
    grid_barrier(bar, NBLK_DEQ);
    int w = tid >> 6, l = tid & 63;
    int apart = l >> 4, a15 = l & 15;
    int cfb = (w & 1) * 32;                 // wave's 32-col half of the panel
    int rt0 = w >> 1;                       // wave's row-tile parity
    const u16* bp0 = Wl + (size_t)(cfb + a15) * 1032 + apart * 8;
    const u16* bp1 = bp0 + 16 * 1032;
    #pragma unroll 1
    for (int it = 1; it <= 39; it++) {
        const u16* zi = (it & 1) ? za : zb;
        u16* zo = (it & 1) ? zb : za;
        for (int rt = rt0; rt < nt; rt += 2) {
            int arow = rows_l[iclamp(base + rt * 16 + a15, 0, 255)];
            const u16* ap = zi + (size_t)arow * 1024 + apart * 8;
            f32x4 acc0 = {0.f, 0.f, 0.f, 0.f}, acc1 = {0.f, 0.f, 0.f, 0.f};
            #pragma unroll
            for (int s = 0; s < 16; s++) {
                short8v av0 = *reinterpret_cast<const short8v*>(ap + s * 64);
                short8v av1 = *reinterpret_cast<const short8v*>(ap + s * 64 + 32);
                short8v b00 = *reinterpret_cast<const short8v*>(bp0 + s * 64);
                short8v b01 = *reinterpret_cast<const short8v*>(bp0 + s * 64 + 32);
                short8v b10 = *reinterpret_cast<const short8v*>(bp1 + s * 64);
                short8v b11 = *reinterpret_cast<const short8v*>(bp1 + s * 64 + 32);
                acc0 = __builtin_amdgcn_mfma_f32_16x16x32_bf16(av0, b00, acc0, 0, 0, 0);
                acc0 = __builtin_amdgcn_mfma_f32_16x16x32_bf16(av1, b01, acc0, 0, 0, 0);
                acc1 = __builtin_amdgcn_mfma_f32_16x16x32_bf16(av0, b10, acc1, 0, 0, 0);
                acc1 = __builtin_amdgcn_mfma_f32_16x16x32_bf16(av1, b11, acc1, 0, 0, 0);
            }
            #pragma unroll
            for (int r = 0; r < 4; r++) {
                int g = rt * 16 + apart * 4 + r;
                if (g < cnt) {
                    int prow = rows_l[iclamp(base + g, 0, 255)];
                    int col = c0 + cfb + a15;
                    float v0 = acc0[r] + c_buf[(size_t)prow * 1024 + col];
                    zo[(size_t)prow * 1024 + col] = f2bf(tanhf(v0));
                    float v1 = acc1[r] + c_buf[(size_t)prow * 1024 + col + 16];
                    zo[(size_t)prow * 1024 + col + 16] = f2bf(tanhf(v1));
                }
            }
        }
        if (it < 39) grid_barrier(bar, (unsigned)NBLK_DEQ * (unsigned)(it + 1));
    }
}

// ---------------- fp32 linear, 16x128 tile (stab1/stab2) ----------------
__global__ __launch_bounds__(256) void lin_k(const float* __restrict__ Abuf, int lda,
                                             const float* __restrict__ Wt, int Kdim,
                                             const float* __restrict__ bias,
                                             float* __restrict__ out_f,
                                             int N, int act) {
    int n0 = blockIdx.x * 128;
    int m0 = blockIdx.y * 16;
    __shared__ float As[16][33];
    __shared__ float Bs[32][129];
    int tid = threadIdx.x;
    int tr = tid >> 5, tc = tid & 31;
    float acc[2][4] = {};
    for (int k0 = 0; k0 < Kdim; k0 += 32) {
        {
            int e = tid;
            #pragma unroll
            for (int rep = 0; rep < 2; rep++) {
                int i = e >> 5, kx = e & 31;
                As[i][kx] = Abuf[(size_t)(m0 + i) * lda + k0 + kx];
                e += 256;
            }
        }
        {
            #pragma unroll
            for (int rep = 0; rep < 16; rep++) {
                int e = tid + rep * 256;
                int o = e >> 5, ix = e & 31;
                Bs[ix][o] = Wt[(size_t)(n0 + o) * Kdim + k0 + ix];
            }
        }
        __syncthreads();
        #pragma unroll
        for (int kx = 0; kx < 32; kx++) {
            float a0 = As[tr][kx], a1 = As[tr + 8][kx];
            float b0 = Bs[kx][tc], b1 = Bs[kx][tc + 32], b2v = Bs[kx][tc + 64], b3 = Bs[kx][tc + 96];
            acc[0][0] += a0 * b0; acc[0][1] += a0 * b1; acc[0][2] += a0 * b2v; acc[0][3] += a0 * b3;
            acc[1][0] += a1 * b0; acc[1][1] += a1 * b1; acc[1][2] += a1 * b2v; acc[1][3] += a1 * b3;
        }
        __syncthreads();
    }
    #pragma unroll
    for (int ii = 0; ii < 2; ii++) {
        int m = m0 + tr + ii * 8;
        #pragma unroll
        for (int j = 0; j < 4; j++) {
            int n = n0 + tc + j * 32;
            float v = acc[ii][j] + bias[n];
            if (act == 1) v = tanhf(v);
            else if (act == 2) v = 1.0f / (1.0f + expf(-v));
            out_f[(size_t)m * N + n] = v;
        }
    }
}

// ---------------- decoder: fp32, 64x256 tile, 8x8 regs, conflict-free LDS, XCD swizzle ----------------
__global__ __launch_bounds__(256) void lin2_k(const float* __restrict__ A, int lda,
                                              const float* __restrict__ Wt, int Kdim,
                                              const float* __restrict__ bias,
                                              float* __restrict__ out_f, int N) {
    // bijective chunked XCD swizzle over 500 blocks (q=62, r=4): the 4 m-tiles of a
    // col-panel become consecutive "orig" ids inside one XCD chunk -> panel fetched by one L2.
    int bid = blockIdx.x;
    int xcd = bid & 7, pos = bid >> 3;
    int orig = (xcd < 4 ? xcd * 63 : 252 + (xcd - 4) * 62) + pos;
    int n0 = (orig >> 2) * 256;
    int m0 = (orig & 3) * 64;
    __shared__ float As[16][68];
    __shared__ float Bs[16][260];
    int tid = threadIdx.x;
    int rg = tid >> 5, cg = tid & 31;
    float acc[8][8] = {};
    for (int k0 = 0; k0 < Kdim; k0 += 16) {
        {
            int m = tid & 63, kq = tid >> 6;
            float4 v = *reinterpret_cast<const float4*>(A + (size_t)(m0 + m) * lda + k0 + kq * 4);
            As[kq * 4 + 0][m] = v.x; As[kq * 4 + 1][m] = v.y;
            As[kq * 4 + 2][m] = v.z; As[kq * 4 + 3][m] = v.w;
        }
        {
            const float* wp = Wt + (size_t)(n0 + tid) * Kdim + k0;
            #pragma unroll
            for (int j = 0; j < 4; j++) {
                float4 v = *reinterpret_cast<const float4*>(wp + j * 4);
                Bs[j * 4 + 0][tid] = v.x; Bs[j * 4 + 1][tid] = v.y;
                Bs[j * 4 + 2][tid] = v.z; Bs[j * 4 + 3][tid] = v.w;
            }
        }
        __syncthreads();
        #pragma unroll
        for (int kx = 0; kx < 16; kx++) {
            float a[8], b[8];
            *reinterpret_cast<float4*>(a)     = *reinterpret_cast<const float4*>(&As[kx][rg * 8]);
            *reinterpret_cast<float4*>(a + 4) = *reinterpret_cast<const float4*>(&As[kx][rg * 8 + 4]);
            #pragma unroll
            for (int j2 = 0; j2 < 4; j2++) {   // strided float2: 2-way even bank spread (free)
                float2 bv = *reinterpret_cast<const float2*>(&Bs[kx][cg * 2 + 64 * j2]);
                b[j2 * 2] = bv.x; b[j2 * 2 + 1] = bv.y;
            }
            #pragma unroll
            for (int i = 0; i < 8; i++)
                #pragma unroll
                for (int j = 0; j < 8; j++)
                    acc[i][j] += a[i] * b[j];
        }
        __syncthreads();
    }
    #pragma unroll
    for (int i = 0; i < 8; i++) {
        int m = m0 + rg * 8 + i;
        #pragma unroll
        for (int j2 = 0; j2 < 4; j2++) {
            int n = n0 + j2 * 64 + cg * 2;
            float2 o;
            o.x = acc[i][j2 * 2] + bias[n];
            o.y = acc[i][j2 * 2 + 1] + bias[n + 1];
            *reinterpret_cast<float2*>(out_f + (size_t)m * N + n) = o;
        }
    }
}

// ---------------- small elementwise ----------------
__global__ void hnext_k(const float* __restrict__ xcat, const float* __restrict__ alocal,
                        const u16* __restrict__ zfin, const float* __restrict__ gamma_ws,
                        float* __restrict__ out_h) {
    int i = blockIdx.x * 256 + threadIdx.x;
    int b = i >> 10, d = i & 1023;
    out_h[i] = xcat[b * 2048 + d] + gamma_ws[b] * alocal[i] * bf2f(zfin[i]);
}

extern "C" void kernel_launch(void* const* d_in, const int* in_sizes, int n_in,
                              void* d_out, int out_size, void* d_ws, size_t ws_size,
                              hipStream_t stream) {
    const float* h     = (const float*)d_in[0];
    const float* fib_s = (const float*)d_in[1];
    const float* fib_e = (const float*)d_in[2];
    const int*   tok   = (const int*)d_in[3];
    const float* opemb = (const float*)d_in[4];
    const float* num_w = (const float*)d_in[5];
    const float* num_b = (const float*)d_in[6];
    const float* addr  = (const float*)d_in[7];
    const float* Wm    = (const float*)d_in[8];
    const float* Um    = (const float*)d_in[9];
    const float* Vm    = (const float*)d_in[10];
    const float* fs_w  = (const float*)d_in[11];
    const float* fs_b  = (const float*)d_in[12];
    const float* fe_w  = (const float*)d_in[13];
    const float* fe_b  = (const float*)d_in[14];
    const float* s1w   = (const float*)d_in[15];
    const float* s1b   = (const float*)d_in[16];
    const float* s2w   = (const float*)d_in[17];
    const float* s2b   = (const float*)d_in[18];
    const float* c1w   = (const float*)d_in[19];
    const float* c1b   = (const float*)d_in[20];
    const float* c2w   = (const float*)d_in[21];
    const float* c2b   = (const float*)d_in[22];
    const float* dec_w = (const float*)d_in[23];
    const float* dec_b = (const float*)d_in[24];

    float* out_h      = (float*)d_out;
    float* out_logits = out_h + BATCH * DIM;                 // element 262144
    float* out_pi     = out_h + BATCH * DIM + BATCH * VOCAB; // element 8454144

    // ALL scratch lives in the logits region (8,192,000 floats). Everything is
    // write-before-read; the decoder GEMM overwrites it at the end.
    float* scr      = out_logits;
    float* xcat     = scr;                   // 256 x 2048 (h | f_emb)
    float* c_buf    = scr + 524288;          // 256 x 1024
    float* stab_h   = scr + 786432;          // 256 x 1024
    float* alocal   = scr + 1048576;         // 256 x 1024
    float* addr_inv = scr + 1310720;         // 8
    float* gamma_ws = scr + 1310728;         // 256
    int* kidx    = (int*)(scr + 1310984);    // 256
    int* order   = (int*)(scr + 1311240);    // 256
    int* tile_k  = (int*)(scr + 1311496);    // 32
    int* tile_r0 = (int*)(scr + 1311528);    // 32
    int* tile_nr = (int*)(scr + 1311560);    // 32
    int* ntiles  = (int*)(scr + 1311592);    // 1
    int* cnt_g   = (int*)(scr + 1311600);    // 7
    int* base_g  = (int*)(scr + 1311608);    // 7
    unsigned* bar = (unsigned*)(scr + 1311616); // 1
    u16* za      = (u16*)(scr + 1311872);    // 256x1024 bf16
    u16* zb      = (u16*)(scr + 1442944);    // 256x1024 bf16
    u16* Wt      = (u16*)(scr + 1574016);    // 7x1024x1024 bf16, ends 5244032 < 8192000

    addr_norm_k<<<1, 256, 0, stream>>>(addr, addr_inv);
    sample_k<<<BATCH, 256, 0, stream>>>(h, fib_s, fib_e, tok, opemb, num_w, num_b, addr,
                                        fs_w, fs_b, fe_w, fe_b, c1w, c1b, c2w, c2b,
                                        addr_inv, xcat, gamma_ws, kidx, out_pi);
    group_k<<<1, 256, 0, stream>>>(kidx, order, tile_k, tile_r0, tile_nr, ntiles,
                                   cnt_g, base_g, bar);
    // one-time W -> Wt (bf16, transposed)
    convt_k<<<dim3(16, 16, KG), 256, 0, stream>>>(Wm, Wt);

    dim3 gg_grid(8, 22);
    // c = h @ U[k]
    gg_k<<<gg_grid, 256, 0, stream>>>(xcat, 2048, Um, nullptr, c_buf, 0,
                                      order, tile_k, tile_r0, tile_nr, ntiles);
    // c += f_emb @ V[k]
    gg_k<<<gg_grid, 256, 0, stream>>>(xcat + 1024, 2048, Vm, c_buf, c_buf, 0,
                                      order, tile_k, tile_r0, tile_nr, ntiles);
    // persistent DEQ: z = f^40(0), W LDS-resident, 39 internal grid barriers
    deq_k<<<NBLK_DEQ, 256, 0, stream>>>(c_buf, za, zb, Wt, order, cnt_g, base_g, bar);
    // stab path
    lin_k<<<dim3(8, 16), 256, 0, stream>>>(xcat, 2048, s1w, 2048, s1b, stab_h, DIM, 1);
    lin_k<<<dim3(8, 16), 256, 0, stream>>>(stab_h, 1024, s2w, 1024, s2b, alocal, DIM, 2);
    // h_next = h + gamma * alpha_local * z_star   (final z is in zb: 39 is odd)
    hnext_k<<<1024, 256, 0, stream>>>(xcat, alocal, zb, gamma_ws, out_h);
    // logits = h_next @ dec_w^T + dec_b (overwrites scratch)
    lin2_k<<<500, 256, 0, stream>>>(out_h, 1024, dec_w, 1024, dec_b, out_logits, VOCAB);
}